// Round 15
// baseline (212.469 us; speedup 1.0000x reference)
//
#include <hip/hip_runtime.h>
#include <hip/hip_bf16.h>

typedef __attribute__((ext_vector_type(4))) float f32x4;
typedef __attribute__((ext_vector_type(8))) short s16x8;
typedef __attribute__((ext_vector_type(4))) int i32x4;
typedef __attribute__((ext_vector_type(4))) unsigned short u16x4;

#define NEG_INF_F (-9.0e15f)
#define LOG2E_F 1.44269504088896340736f
#define N_ROWS 8192
#define F_DIM 256

__device__ __forceinline__ unsigned short f2bf(float f) {
    unsigned int u = __builtin_bit_cast(unsigned int, f);
    u += 0x7fffu + ((u >> 16) & 1u);   // round-to-nearest-even
    return (unsigned short)(u >> 16);
}

__device__ __forceinline__ float fast_exp2(float x) {
#if __has_builtin(__builtin_amdgcn_exp2f)
    return __builtin_amdgcn_exp2f(x);   // raw v_exp_f32; big-neg -> exactly 0.0
#else
    return exp2f(x);
#endif
}

__device__ __forceinline__ short f2bf_fast(float f) {
    __hip_bfloat16 b = __float2bfloat16(f);   // native cast -> v_cvt_pk_bf16_f32 pairs
    return __builtin_bit_cast(short, b);
}

// ------------- Kernel 0: pack adj (int32 0/1, 256MB) -> bitmask (8MB) ----
// (per-thread packer, r7/r8-proven bit order; do NOT swap for ballot)
__global__ __launch_bounds__(256) void k0_pack(const int* __restrict__ adj,
                                               unsigned* __restrict__ mask32) {
    const int t0 = (int)blockIdx.x * 256 + (int)threadIdx.x;
    const int nt = (int)gridDim.x * 256;
#pragma unroll 1
    for (int w = t0; w < (N_ROWS * N_ROWS / 32); w += nt) {
        const int* p = adj + (size_t)w * 32;
        unsigned m = 0;
#pragma unroll
        for (int i = 0; i < 8; ++i) {
            i32x4 v = *(const i32x4*)(p + i * 4);
            m |= (v[0] > 0 ? 1u : 0u) << (i * 4);
            m |= (v[1] > 0 ? 2u : 0u) << (i * 4);
            m |= (v[2] > 0 ? 4u : 0u) << (i * 4);
            m |= (v[3] > 0 ? 8u : 0u) << (i * 4);
        }
        mask32[w] = m;
    }
}

// ------------- Kernel 1: hTp = bf16(x @ W^T), packed [k/8][feat][k%8] ----
__global__ __launch_bounds__(256) void k1_gemm(const float* __restrict__ x,
                                               const float* __restrict__ W,
                                               unsigned short* __restrict__ hTp) {
    __shared__ float xT[128][64];
    __shared__ float wT[128][64];
    const int tid = threadIdx.x;
    const int rb = blockIdx.x >> 2, fbk = blockIdx.x & 3;
    const int row0 = rb * 64, f0 = fbk * 64;
    const int rs = tid >> 2, cs = tid & 3;
    const int r0 = (tid & 15) * 4, fc = (tid >> 4) * 4;
    float acc[4][4];
#pragma unroll
    for (int i = 0; i < 4; ++i)
#pragma unroll
        for (int j = 0; j < 4; ++j) acc[i][j] = 0.0f;

#pragma unroll 1
    for (int p = 0; p < 2; ++p) {
        const int kb = p * 128;
        if (p) __syncthreads();
        const float* xrow = x + (size_t)(row0 + rs) * F_DIM + kb + cs * 32;
        const float* wrow = W + (size_t)(f0 + rs) * F_DIM + kb + cs * 32;
#pragma unroll
        for (int i = 0; i < 8; ++i) {
            f32x4 xv = *(const f32x4*)(xrow + i * 4);
            f32x4 wv = *(const f32x4*)(wrow + i * 4);
#pragma unroll
            for (int jj = 0; jj < 4; ++jj) {
                xT[cs * 32 + i * 4 + jj][rs] = xv[jj];
                wT[cs * 32 + i * 4 + jj][rs] = wv[jj];
            }
        }
        __syncthreads();
#pragma unroll 4
        for (int kk = 0; kk < 128; ++kk) {
            f32x4 xv = *(const f32x4*)&xT[kk][r0];
            f32x4 wv = *(const f32x4*)&wT[kk][fc];
#pragma unroll
            for (int i = 0; i < 4; ++i)
#pragma unroll
                for (int j = 0; j < 4; ++j)
                    acc[i][j] = fmaf(xv[i], wv[j], acc[i][j]);
        }
    }
    const int kblk = (row0 + r0) >> 3, kslot = (row0 + r0) & 7;
#pragma unroll
    for (int j = 0; j < 4; ++j) {
        u16x4 t;
        t[0] = f2bf(acc[0][j]); t[1] = f2bf(acc[1][j]);
        t[2] = f2bf(acc[2][j]); t[3] = f2bf(acc[3][j]);
        *(u16x4*)(hTp + (size_t)kblk * 2048 + (f0 + fc + j) * 8 + kslot) = t;
    }
}

// ------------- Kernel 1a: va1 = W^T a1, va2 = W^T a2 ---------------------
__global__ __launch_bounds__(256) void kva(const float* __restrict__ W,
                                           const float* __restrict__ a,
                                           float* __restrict__ va) {
    const int k = threadIdx.x;
    const int b = blockIdx.x;
    const float* av = a + b * 256;
    float s0 = 0.f, s1 = 0.f, s2 = 0.f, s3 = 0.f;
#pragma unroll 8
    for (int f = 0; f < 256; f += 4) {
        s0 = fmaf(av[f],     W[(size_t)f * 256 + k],       s0);
        s1 = fmaf(av[f + 1], W[(size_t)(f + 1) * 256 + k], s1);
        s2 = fmaf(av[f + 2], W[(size_t)(f + 2) * 256 + k], s2);
        s3 = fmaf(av[f + 3], W[(size_t)(f + 3) * 256 + k], s3);
    }
    va[b * 256 + k] = (s0 + s1) + (s2 + s3);
}

// ------------- Kernel 1b: s1 = x@va1, s2 = x@va2 (f32) -------------------
__global__ __launch_bounds__(256) void k1b_s(const float* __restrict__ x,
                                             const float* __restrict__ va,
                                             float* __restrict__ s1,
                                             float* __restrict__ s2) {
    const int tid = threadIdx.x, lane = tid & 63, w = tid >> 6;
    f32x4 a1 = *(const f32x4*)(va + lane * 4);
    f32x4 a2 = *(const f32x4*)(va + 256 + lane * 4);
    const int row0 = blockIdx.x * 32 + w * 8;
#pragma unroll 1
    for (int rr = 0; rr < 8; ++rr) {
        const int row = row0 + rr;
        f32x4 hv = *(const f32x4*)(x + (size_t)row * F_DIM + lane * 4);
        float p1 = hv[0] * a1[0] + hv[1] * a1[1] + hv[2] * a1[2] + hv[3] * a1[3];
        float p2 = hv[0] * a2[0] + hv[1] * a2[1] + hv[2] * a2[2] + hv[3] * a2[3];
#pragma unroll
        for (int o = 32; o; o >>= 1) { p1 += __shfl_xor(p1, o); p2 += __shfl_xor(p2, o); }
        if (lane == 0) { s1[row] = p1; s2[row] = p2; }
    }
}

// ------------- Kernel 1c: M[i] = max over unmasked j of s2[j] ------------
__global__ __launch_bounds__(256) void kmax(const unsigned* __restrict__ mask32,
                                            const float* __restrict__ s2,
                                            float* __restrict__ Mrow) {
    __shared__ float s2l[8192];
    const int tid = threadIdx.x, lane = tid & 63, wv = tid >> 6;
#pragma unroll
    for (int i = 0; i < 8; ++i) {
        const int idx = (i * 256 + tid) * 4;
        *(f32x4*)&s2l[idx] = *(const f32x4*)(s2 + idx);
    }
    __syncthreads();
    const int row = (int)blockIdx.x * 4 + wv;
    const unsigned* __restrict__ mr = mask32 + (size_t)row * 256;
    float vmax = NEG_INF_F;
#pragma unroll 1
    for (int wi = 0; wi < 4; ++wi) {
        const unsigned m = mr[lane * 4 + wi];
        const int kb = (lane * 4 + wi) * 32;
#pragma unroll
        for (int cc = 0; cc < 8; ++cc) {
            const int c = (cc + lane) & 7;
            f32x4 v = *(const f32x4*)&s2l[kb + c * 4];
            const unsigned sh = (unsigned)(c * 4);
            vmax = fmaxf(vmax, ((m >> (sh + 0)) & 1u) ? v[0] : NEG_INF_F);
            vmax = fmaxf(vmax, ((m >> (sh + 1)) & 1u) ? v[1] : NEG_INF_F);
            vmax = fmaxf(vmax, ((m >> (sh + 2)) & 1u) ? v[2] : NEG_INF_F);
            vmax = fmaxf(vmax, ((m >> (sh + 3)) & 1u) ? v[3] : NEG_INF_F);
        }
    }
#pragma unroll
    for (int o = 32; o; o >>= 1) vmax = fmaxf(vmax, __shfl_xor(vmax, o));
    if (lane == 0) Mrow[row] = vmax;
}

// ------------- Kernel 1d: E1 = e^{s2}, E2 = e^{0.2 s2} (f32, 32KB each) --
__global__ __launch_bounds__(256) void kE(const float* __restrict__ s2,
                                          float* __restrict__ E1f,
                                          float* __restrict__ E2f) {
    const int i = (int)blockIdx.x * 256 + (int)threadIdx.x;
    const float s = s2[i];
    E1f[i] = fast_exp2(s * LOG2E_F);
    E2f[i] = fast_exp2(0.2f * s * LOG2E_F);
}

// ------------- Kernel 2: fused masked softmax + PV -----------------------
// r11 geometry VERBATIM (grid 512 = 256 rowblocks x 2 feat halves, nt=8,
// ping-pong bA/bB, ones-MFMA l). Softmax via PRECOMPUTED branch exps:
//   q = mask ? (cond ? E1[j]*c1 : E2[j]*c2) : 0,  cond = s_j > -s_i
// == exp(leaky(si+sj) - m) exactly (leaky continuous at boundary).
// No per-pair exp/fmax/fmaf -> shallow VALU chain.

#define P_ONE(D, SV, E1, E2, BIT, TN, C1, C2)                                 \
    { const bool cnd_ = (SV) > (TN);                                          \
      const float e_ = cnd_ ? (E1) : (E2);                                    \
      const float cc_ = cnd_ ? (C1) : (C2);                                   \
      D = (bb_ & (BIT)) ? e_ * cc_ : 0.0f; }

#define RG_STEP(ACC, ACCL, BFR, MW, TN, C1, C2)                               \
    {                                                                         \
        const unsigned bb_ = ((MW) >> koff) & 0xffu;                          \
        float p0_, p1_, p2_, p3_, p4_, p5_, p6_, p7_;                         \
        P_ONE(p0_, svA_[0], e1A_[0], e2A_[0], 1u,   TN, C1, C2)               \
        P_ONE(p1_, svA_[1], e1A_[1], e2A_[1], 2u,   TN, C1, C2)               \
        P_ONE(p2_, svA_[2], e1A_[2], e2A_[2], 4u,   TN, C1, C2)               \
        P_ONE(p3_, svA_[3], e1A_[3], e2A_[3], 8u,   TN, C1, C2)               \
        P_ONE(p4_, svB_[0], e1B_[0], e2B_[0], 16u,  TN, C1, C2)               \
        P_ONE(p5_, svB_[1], e1B_[1], e2B_[1], 32u,  TN, C1, C2)               \
        P_ONE(p6_, svB_[2], e1B_[2], e2B_[2], 64u,  TN, C1, C2)               \
        P_ONE(p7_, svB_[3], e1B_[3], e2B_[3], 128u, TN, C1, C2)               \
        s16x8 af_;                                                            \
        af_[0] = f2bf_fast(p0_); af_[1] = f2bf_fast(p1_);                     \
        af_[2] = f2bf_fast(p2_); af_[3] = f2bf_fast(p3_);                     \
        af_[4] = f2bf_fast(p4_); af_[5] = f2bf_fast(p5_);                     \
        af_[6] = f2bf_fast(p6_); af_[7] = f2bf_fast(p7_);                     \
        _Pragma("unroll")                                                     \
        for (int nt_ = 0; nt_ < 8; ++nt_)                                     \
            ACC[nt_] = __builtin_amdgcn_mfma_f32_16x16x32_bf16(af_, BFR[nt_], ACC[nt_], 0, 0, 0); \
        ACCL = __builtin_amdgcn_mfma_f32_16x16x32_bf16(af_, bones, ACCL, 0, 0, 0); \
    }

#define HALF_STEP(BFR, MWA, MWB, K)                                           \
    {                                                                         \
        const f32x4 svA_ = *(const f32x4*)(s2 + (K) + koff);                  \
        const f32x4 svB_ = *(const f32x4*)(s2 + (K) + koff + 4);              \
        const f32x4 e1A_ = *(const f32x4*)(E1f + (K) + koff);                 \
        const f32x4 e1B_ = *(const f32x4*)(E1f + (K) + koff + 4);             \
        const f32x4 e2A_ = *(const f32x4*)(E2f + (K) + koff);                 \
        const f32x4 e2B_ = *(const f32x4*)(E2f + (K) + koff + 4);             \
        RG_STEP(accA, accLA, BFR, MWA, TnA, c1A, c2A)                         \
        RG_STEP(accB, accLB, BFR, MWB, TnB, c1B, c2B)                         \
    }

#define LOAD_B(DST, K)                                                        \
    _Pragma("unroll")                                                         \
    for (int nt_ = 0; nt_ < 8; ++nt_)                                         \
        DST[nt_] = *(const s16x8*)(hTp + (unsigned)(((K) >> 3) + kg) * 2048u + vb + (unsigned)(nt_ * 128));

__global__ __launch_bounds__(256) void k2_attn(const unsigned* __restrict__ mask32,
                                               const unsigned short* __restrict__ hTp,
                                               const float* __restrict__ s1,
                                               const float* __restrict__ s2,
                                               const float* __restrict__ Mrow,
                                               const float* __restrict__ E1f,
                                               const float* __restrict__ E2f,
                                               float* __restrict__ out) {
    __shared__ float lbuf[4][2][16];            // [wc][rg][row]
    __shared__ float accbuf[3][16][132];        // [wc-1][row][feat] (+4 pad)

    const int tid = threadIdx.x;
    const int lane = tid & 63;
    const int wc = tid >> 6;                    // 0..3 key-chunk
    const int lane15 = lane & 15, kg = lane >> 4, koff = kg * 8;
    const int rowblk = (int)blockIdx.x >> 1;
    const int fh = (int)blockIdx.x & 1;
    const int row0 = rowblk * 32;
    const int mrowA = row0 + lane15, mrowB = row0 + 16 + lane15;
    const int fb = fh * 128;
    const int kbase = wc * 2048;
    const float siA = s1[mrowA], siB = s1[mrowB];
    const float tmxA = siA + Mrow[mrowA], tmxB = siB + Mrow[mrowB];
    const float mCA = fmaxf(tmxA, 0.2f * tmxA) * LOG2E_F;
    const float mCB = fmaxf(tmxB, 0.2f * tmxB) * LOG2E_F;
    // branch constants: q = (cond ? E1*c1 : E2*c2), cond = sv > -si
    const float TnA = -siA, TnB = -siB;
    const float c1A = fast_exp2(fmaf(siA, LOG2E_F, -mCA));
    const float c2A = fast_exp2(fmaf(0.2f * siA, LOG2E_F, -mCA));
    const float c1B = fast_exp2(fmaf(siB, LOG2E_F, -mCB));
    const float c2B = fast_exp2(fmaf(0.2f * siB, LOG2E_F, -mCB));
    const unsigned* __restrict__ mA32 = mask32 + (size_t)mrowA * 256;
    const unsigned* __restrict__ mB32 = mask32 + (size_t)mrowB * 256;

    f32x4 accA[8], accB[8], accLA, accLB;
#pragma unroll
    for (int nt = 0; nt < 8; ++nt) {
        f32x4 z = {0.f, 0.f, 0.f, 0.f};
        accA[nt] = z; accB[nt] = z;
    }
    { f32x4 z = {0.f, 0.f, 0.f, 0.f}; accLA = z; accLB = z; }

    s16x8 bones;
#pragma unroll
    for (int j = 0; j < 8; ++j) bones[j] = (short)0x3F80;   // bf16 1.0

    const unsigned vb = (unsigned)(fb + lane15) * 8u;

    s16x8 bA[8], bB[8];
    LOAD_B(bA, kbase)
    unsigned mwA = mA32[kbase >> 5], mwB = mB32[kbase >> 5];

#pragma unroll 1
    for (int it = 0; it < 64; it += 2) {
        const int k0 = kbase + it * 32;
        const int k1 = k0 + 32;
        const int k2n = (it + 2 < 64) ? (k0 + 64) : kbase;   // wrap: loaded, unused

        LOAD_B(bB, k1)
        const unsigned mwnA = mA32[k1 >> 5], mwnB = mB32[k1 >> 5];

        HALF_STEP(bA, mwA, mwB, k0);

        LOAD_B(bA, k2n)
        mwA = mA32[k2n >> 5]; mwB = mB32[k2n >> 5];

        HALF_STEP(bB, mwnA, mwnB, k1);
    }

    // l: ones-MFMA already reduced over keys; every D column holds the row sum.
    if (lane15 == 0) {
#pragma unroll
        for (int r = 0; r < 4; ++r) {
            lbuf[wc][0][kg * 4 + r] = accLA[r];
            lbuf[wc][1][kg * 4 + r] = accLB[r];
        }
    }

    // ---- phase A: merge + write row-group 0 ----
    if (wc > 0) {
#pragma unroll
        for (int r = 0; r < 4; ++r)
#pragma unroll
            for (int nt = 0; nt < 8; ++nt)
                accbuf[wc - 1][kg * 4 + r][nt * 16 + lane15] = accA[nt][r];
    }
    __syncthreads();
    if (wc == 0) {
#pragma unroll
        for (int r = 0; r < 4; ++r) {
            const int dr = kg * 4 + r;
            const float lt = (lbuf[0][0][dr] + lbuf[1][0][dr]) + (lbuf[2][0][dr] + lbuf[3][0][dr]);
            const float inv = 1.0f / lt;
            float* orow_p = out + (size_t)(row0 + dr) * F_DIM + fb + lane15;
#pragma unroll
            for (int nt = 0; nt < 8; ++nt) {
                const float v = accA[nt][r] + accbuf[0][dr][nt * 16 + lane15]
                              + accbuf[1][dr][nt * 16 + lane15]
                              + accbuf[2][dr][nt * 16 + lane15];
                orow_p[nt * 16] = v * inv;
            }
        }
    }
    __syncthreads();

    // ---- phase B: merge + write row-group 1 ----
    if (wc > 0) {
#pragma unroll
        for (int r = 0; r < 4; ++r)
#pragma unroll
            for (int nt = 0; nt < 8; ++nt)
                accbuf[wc - 1][kg * 4 + r][nt * 16 + lane15] = accB[nt][r];
    }
    __syncthreads();
    if (wc == 0) {
#pragma unroll
        for (int r = 0; r < 4; ++r) {
            const int dr = kg * 4 + r;
            const float lt = (lbuf[0][1][dr] + lbuf[1][1][dr]) + (lbuf[2][1][dr] + lbuf[3][1][dr]);
            const float inv = 1.0f / lt;
            float* orow_p = out + (size_t)(row0 + 16 + dr) * F_DIM + fb + lane15;
#pragma unroll
            for (int nt = 0; nt < 8; ++nt) {
                const float v = accB[nt][r] + accbuf[0][dr][nt * 16 + lane15]
                              + accbuf[1][dr][nt * 16 + lane15]
                              + accbuf[2][dr][nt * 16 + lane15];
                orow_p[nt * 16] = v * inv;
            }
        }
    }
}

extern "C" void kernel_launch(void* const* d_in, const int* in_sizes, int n_in,
                              void* d_out, int out_size, void* d_ws, size_t ws_size,
                              hipStream_t stream) {
    (void)in_sizes; (void)n_in; (void)out_size; (void)ws_size;
    const float* x  = (const float*)d_in[0];
    const int*  adj = (const int*)d_in[1];
    const float* W  = (const float*)d_in[2];
    const float* a  = (const float*)d_in[3];
    float* out = (float*)d_out;
    char* ws = (char*)d_ws;
    // total ws use: 12.19 MB
    unsigned short* hTp = (unsigned short*)ws;                      // 4 MB  packed bf16
    float* s1 = (float*)(ws + (4 << 20));                           // 32 KB
    float* s2 = (float*)(ws + (4 << 20) + (32 << 10));              // 32 KB
    float* va = (float*)(ws + (4 << 20) + (64 << 10));              // 2 KB
    float* Mr = (float*)(ws + (4 << 20) + (96 << 10));              // 32 KB
    float* E1 = (float*)(ws + (4 << 20) + (128 << 10));             // 32 KB
    float* E2 = (float*)(ws + (4 << 20) + (160 << 10));             // 32 KB
    unsigned* mk = (unsigned*)(ws + (4 << 20) + (192 << 10));       // 8 MB

    k0_pack<<<2048, 256, 0, stream>>>(adj, mk);
    k1_gemm<<<512, 256, 0, stream>>>(x, W, hTp);
    kva<<<2, 256, 0, stream>>>(W, a, va);
    k1b_s<<<256, 256, 0, stream>>>(x, va, s1, s2);
    kmax<<<2048, 256, 0, stream>>>(mk, s2, Mr);
    kE<<<32, 256, 0, stream>>>(s2, E1, E2);
    k2_attn<<<512, 256, 0, stream>>>(mk, hTp, s1, s2, Mr, E1, E2, out);
}

// Round 16
// 189.129 us; speedup vs baseline: 1.1234x; 1.1234x over previous
//
#include <hip/hip_runtime.h>
#include <hip/hip_bf16.h>

typedef __attribute__((ext_vector_type(4))) float f32x4;
typedef __attribute__((ext_vector_type(8))) short s16x8;
typedef __attribute__((ext_vector_type(4))) int i32x4;
typedef __attribute__((ext_vector_type(4))) unsigned short u16x4;

#define NEG_INF_F (-9.0e15f)
#define LOG2E_F 1.44269504088896340736f
#define N_ROWS 8192
#define F_DIM 256

__device__ __forceinline__ unsigned short f2bf(float f) {
    unsigned int u = __builtin_bit_cast(unsigned int, f);
    u += 0x7fffu + ((u >> 16) & 1u);   // round-to-nearest-even
    return (unsigned short)(u >> 16);
}

__device__ __forceinline__ float fast_exp2(float x) {
#if __has_builtin(__builtin_amdgcn_exp2f)
    return __builtin_amdgcn_exp2f(x);   // raw v_exp_f32; big-neg -> exactly 0.0
#else
    return exp2f(x);
#endif
}

__device__ __forceinline__ short f2bf_fast(float f) {
    __hip_bfloat16 b = __float2bfloat16(f);   // native cast -> v_cvt_pk_bf16_f32 pairs
    return __builtin_bit_cast(short, b);
}

// ------------- Kernel 0: pack adj (int32 0/1, 256MB) -> bitmask (8MB) ----
__global__ __launch_bounds__(256) void k0_pack(const int* __restrict__ adj,
                                               unsigned* __restrict__ mask32) {
    const int t0 = (int)blockIdx.x * 256 + (int)threadIdx.x;
    const int nt = (int)gridDim.x * 256;
#pragma unroll 1
    for (int w = t0; w < (N_ROWS * N_ROWS / 32); w += nt) {
        const int* p = adj + (size_t)w * 32;
        unsigned m = 0;
#pragma unroll
        for (int i = 0; i < 8; ++i) {
            i32x4 v = *(const i32x4*)(p + i * 4);
            m |= (v[0] > 0 ? 1u : 0u) << (i * 4);
            m |= (v[1] > 0 ? 2u : 0u) << (i * 4);
            m |= (v[2] > 0 ? 4u : 0u) << (i * 4);
            m |= (v[3] > 0 ? 8u : 0u) << (i * 4);
        }
        mask32[w] = m;
    }
}

// ------------- Kernel 1: hTp = bf16(x @ W^T), packed [k/8][feat][k%8] ----
__global__ __launch_bounds__(256) void k1_gemm(const float* __restrict__ x,
                                               const float* __restrict__ W,
                                               unsigned short* __restrict__ hTp) {
    __shared__ float xT[128][64];
    __shared__ float wT[128][64];
    const int tid = threadIdx.x;
    const int rb = blockIdx.x >> 2, fbk = blockIdx.x & 3;
    const int row0 = rb * 64, f0 = fbk * 64;
    const int rs = tid >> 2, cs = tid & 3;
    const int r0 = (tid & 15) * 4, fc = (tid >> 4) * 4;
    float acc[4][4];
#pragma unroll
    for (int i = 0; i < 4; ++i)
#pragma unroll
        for (int j = 0; j < 4; ++j) acc[i][j] = 0.0f;

#pragma unroll 1
    for (int p = 0; p < 2; ++p) {
        const int kb = p * 128;
        if (p) __syncthreads();
        const float* xrow = x + (size_t)(row0 + rs) * F_DIM + kb + cs * 32;
        const float* wrow = W + (size_t)(f0 + rs) * F_DIM + kb + cs * 32;
#pragma unroll
        for (int i = 0; i < 8; ++i) {
            f32x4 xv = *(const f32x4*)(xrow + i * 4);
            f32x4 wv = *(const f32x4*)(wrow + i * 4);
#pragma unroll
            for (int jj = 0; jj < 4; ++jj) {
                xT[cs * 32 + i * 4 + jj][rs] = xv[jj];
                wT[cs * 32 + i * 4 + jj][rs] = wv[jj];
            }
        }
        __syncthreads();
#pragma unroll 4
        for (int kk = 0; kk < 128; ++kk) {
            f32x4 xv = *(const f32x4*)&xT[kk][r0];
            f32x4 wv = *(const f32x4*)&wT[kk][fc];
#pragma unroll
            for (int i = 0; i < 4; ++i)
#pragma unroll
                for (int j = 0; j < 4; ++j)
                    acc[i][j] = fmaf(xv[i], wv[j], acc[i][j]);
        }
    }
    const int kblk = (row0 + r0) >> 3, kslot = (row0 + r0) & 7;
#pragma unroll
    for (int j = 0; j < 4; ++j) {
        u16x4 t;
        t[0] = f2bf(acc[0][j]); t[1] = f2bf(acc[1][j]);
        t[2] = f2bf(acc[2][j]); t[3] = f2bf(acc[3][j]);
        *(u16x4*)(hTp + (size_t)kblk * 2048 + (f0 + fc + j) * 8 + kslot) = t;
    }
}

// ------------- Kernel 1a: va1 = W^T a1, va2 = W^T a2 ---------------------
__global__ __launch_bounds__(256) void kva(const float* __restrict__ W,
                                           const float* __restrict__ a,
                                           float* __restrict__ va) {
    const int k = threadIdx.x;
    const int b = blockIdx.x;
    const float* av = a + b * 256;
    float s0 = 0.f, s1 = 0.f, s2 = 0.f, s3 = 0.f;
#pragma unroll 8
    for (int f = 0; f < 256; f += 4) {
        s0 = fmaf(av[f],     W[(size_t)f * 256 + k],       s0);
        s1 = fmaf(av[f + 1], W[(size_t)(f + 1) * 256 + k], s1);
        s2 = fmaf(av[f + 2], W[(size_t)(f + 2) * 256 + k], s2);
        s3 = fmaf(av[f + 3], W[(size_t)(f + 3) * 256 + k], s3);
    }
    va[b * 256 + k] = (s0 + s1) + (s2 + s3);
}

// ------------- Kernel 1b: s1 = x@va1, s2 = x@va2 (f32) -------------------
__global__ __launch_bounds__(256) void k1b_s(const float* __restrict__ x,
                                             const float* __restrict__ va,
                                             float* __restrict__ s1,
                                             float* __restrict__ s2) {
    const int tid = threadIdx.x, lane = tid & 63, w = tid >> 6;
    f32x4 a1 = *(const f32x4*)(va + lane * 4);
    f32x4 a2 = *(const f32x4*)(va + 256 + lane * 4);
    const int row0 = blockIdx.x * 32 + w * 8;
#pragma unroll 1
    for (int rr = 0; rr < 8; ++rr) {
        const int row = row0 + rr;
        f32x4 hv = *(const f32x4*)(x + (size_t)row * F_DIM + lane * 4);
        float p1 = hv[0] * a1[0] + hv[1] * a1[1] + hv[2] * a1[2] + hv[3] * a1[3];
        float p2 = hv[0] * a2[0] + hv[1] * a2[1] + hv[2] * a2[2] + hv[3] * a2[3];
#pragma unroll
        for (int o = 32; o; o >>= 1) { p1 += __shfl_xor(p1, o); p2 += __shfl_xor(p2, o); }
        if (lane == 0) { s1[row] = p1; s2[row] = p2; }
    }
}

// ------------- Kernel 1c: M[i] = max over unmasked j of s2[j] ------------
__global__ __launch_bounds__(256) void kmax(const unsigned* __restrict__ mask32,
                                            const float* __restrict__ s2,
                                            float* __restrict__ Mrow) {
    __shared__ float s2l[8192];
    const int tid = threadIdx.x, lane = tid & 63, wv = tid >> 6;
#pragma unroll
    for (int i = 0; i < 8; ++i) {
        const int idx = (i * 256 + tid) * 4;
        *(f32x4*)&s2l[idx] = *(const f32x4*)(s2 + idx);
    }
    __syncthreads();
    const int row = (int)blockIdx.x * 4 + wv;
    const unsigned* __restrict__ mr = mask32 + (size_t)row * 256;
    float vmax = NEG_INF_F;
#pragma unroll 1
    for (int wi = 0; wi < 4; ++wi) {
        const unsigned m = mr[lane * 4 + wi];
        const int kb = (lane * 4 + wi) * 32;
#pragma unroll
        for (int cc = 0; cc < 8; ++cc) {
            const int c = (cc + lane) & 7;
            f32x4 v = *(const f32x4*)&s2l[kb + c * 4];
            const unsigned sh = (unsigned)(c * 4);
            vmax = fmaxf(vmax, ((m >> (sh + 0)) & 1u) ? v[0] : NEG_INF_F);
            vmax = fmaxf(vmax, ((m >> (sh + 1)) & 1u) ? v[1] : NEG_INF_F);
            vmax = fmaxf(vmax, ((m >> (sh + 2)) & 1u) ? v[2] : NEG_INF_F);
            vmax = fmaxf(vmax, ((m >> (sh + 3)) & 1u) ? v[3] : NEG_INF_F);
        }
    }
#pragma unroll
    for (int o = 32; o; o >>= 1) vmax = fmaxf(vmax, __shfl_xor(vmax, o));
    if (lane == 0) Mrow[row] = vmax;
}

// ------------- Kernel 2: fused masked softmax + PV (two key-half passes) -
// Block: 64 rows x 128 feats x 4096 keys; grid 256 = 64-rowblocks x 2 fh
// (fh = blockIdx&1 -> even/odd XCDs each cache only their 1MB hTp slice).
// 4 waves = 4 key-chunks of 1024; per wave 4 ROW-GROUPS x 8 nt (acc 128 VGPR,
// 1 blk/CU -> VGPR-pressure-immune). r11-proven ping-pong + raw-exp softmax.
// ADD=0: out = partial, Lp = l-partial. ADD=1: out = (out+partial)/(Lp+l).

#define P_ONE(D, SV, BIT, SI, MC)                                             \
    { float t_ = (SI) + (SV); t_ = fmaxf(t_, 0.2f * t_);                      \
      D = fast_exp2(fmaf(((bb_ & (BIT)) ? t_ : NEG_INF_F), LOG2E_F, -(MC))); }

#define RG_STEP(ACC, ACCL, BFR, MW, SI, MC)                                   \
    {                                                                         \
        const unsigned bb_ = ((MW) >> koff) & 0xffu;                          \
        float p0_, p1_, p2_, p3_, p4_, p5_, p6_, p7_;                         \
        P_ONE(p0_, svA_[0], 1u, SI, MC)   P_ONE(p1_, svA_[1], 2u, SI, MC)     \
        P_ONE(p2_, svA_[2], 4u, SI, MC)   P_ONE(p3_, svA_[3], 8u, SI, MC)     \
        P_ONE(p4_, svB_[0], 16u, SI, MC)  P_ONE(p5_, svB_[1], 32u, SI, MC)    \
        P_ONE(p6_, svB_[2], 64u, SI, MC)  P_ONE(p7_, svB_[3], 128u, SI, MC)   \
        s16x8 af_;                                                            \
        af_[0] = f2bf_fast(p0_); af_[1] = f2bf_fast(p1_);                     \
        af_[2] = f2bf_fast(p2_); af_[3] = f2bf_fast(p3_);                     \
        af_[4] = f2bf_fast(p4_); af_[5] = f2bf_fast(p5_);                     \
        af_[6] = f2bf_fast(p6_); af_[7] = f2bf_fast(p7_);                     \
        _Pragma("unroll")                                                     \
        for (int nt_ = 0; nt_ < 8; ++nt_)                                     \
            ACC[nt_] = __builtin_amdgcn_mfma_f32_16x16x32_bf16(af_, BFR[nt_], ACC[nt_], 0, 0, 0); \
        ACCL = __builtin_amdgcn_mfma_f32_16x16x32_bf16(af_, bones, ACCL, 0, 0, 0); \
    }

#define HALF_STEP(BFR, MWA, MWB, MWC, MWD, K)                                 \
    {                                                                         \
        const f32x4 svA_ = *(const f32x4*)(s2 + (K) + koff);                  \
        const f32x4 svB_ = *(const f32x4*)(s2 + (K) + koff + 4);              \
        RG_STEP(accA, accLA, BFR, MWA, siA, mCA)                              \
        RG_STEP(accB, accLB, BFR, MWB, siB, mCB)                              \
        RG_STEP(accC, accLC, BFR, MWC, siC, mCC)                              \
        RG_STEP(accD, accLD, BFR, MWD, siD, mCD)                              \
    }

#define LOAD_B(DST, K)                                                        \
    _Pragma("unroll")                                                         \
    for (int nt_ = 0; nt_ < 8; ++nt_)                                         \
        DST[nt_] = *(const s16x8*)(hTp + (unsigned)(((K) >> 3) + kg) * 2048u + vb + (unsigned)(nt_ * 128));

// merge + output phase for one row-group (r11-proven pattern)
#define OUT_PHASE(ACC, RG, RGOFF)                                             \
    if (wc > 0) {                                                             \
        _Pragma("unroll")                                                     \
        for (int r = 0; r < 4; ++r)                                           \
            _Pragma("unroll")                                                 \
            for (int nt = 0; nt < 8; ++nt)                                    \
                accbuf[wc - 1][kg * 4 + r][nt * 16 + lane15] = ACC[nt][r];    \
    }                                                                         \
    __syncthreads();                                                          \
    if (wc == 0) {                                                            \
        _Pragma("unroll")                                                     \
        for (int r = 0; r < 4; ++r) {                                         \
            const int dr = kg * 4 + r;                                        \
            const int row = row0 + (RGOFF) + dr;                              \
            const float lt = (lbuf[0][RG][dr] + lbuf[1][RG][dr])              \
                           + (lbuf[2][RG][dr] + lbuf[3][RG][dr]);             \
            float* orow_p = out + (size_t)row * F_DIM + fb + lane15;          \
            if (ADD) {                                                        \
                const float inv = 1.0f / (Lp[row] + lt);                      \
                _Pragma("unroll")                                             \
                for (int nt = 0; nt < 8; ++nt) {                              \
                    const float v = ACC[nt][r] + accbuf[0][dr][nt * 16 + lane15] \
                                  + accbuf[1][dr][nt * 16 + lane15]           \
                                  + accbuf[2][dr][nt * 16 + lane15];          \
                    orow_p[nt * 16] = (orow_p[nt * 16] + v) * inv;            \
                }                                                             \
            } else {                                                          \
                _Pragma("unroll")                                             \
                for (int nt = 0; nt < 8; ++nt) {                              \
                    const float v = ACC[nt][r] + accbuf[0][dr][nt * 16 + lane15] \
                                  + accbuf[1][dr][nt * 16 + lane15]           \
                                  + accbuf[2][dr][nt * 16 + lane15];          \
                    orow_p[nt * 16] = v;                                      \
                }                                                             \
                if (fh == 0 && lane15 == 0) Lp[row] = lt;                     \
            }                                                                 \
        }                                                                     \
    }                                                                         \
    __syncthreads();

template <int ADD>
__global__ __launch_bounds__(256) void k2_attn(const unsigned* __restrict__ mask32,
                                               const unsigned short* __restrict__ hTp,
                                               const float* __restrict__ s1,
                                               const float* __restrict__ s2,
                                               const float* __restrict__ Mrow,
                                               float* __restrict__ Lp,
                                               float* __restrict__ out) {
    __shared__ float lbuf[4][4][16];            // [wc][rg][row]
    __shared__ float accbuf[3][16][132];        // [wc-1][row][feat] (+4 pad)

    const int tid = threadIdx.x;
    const int lane = tid & 63;
    const int wc = tid >> 6;                    // 0..3 key-chunk
    const int lane15 = lane & 15, kg = lane >> 4, koff = kg * 8;
    const int rowblk = (int)blockIdx.x >> 1;
    const int fh = (int)blockIdx.x & 1;
    const int row0 = rowblk * 64;
    const int mrowA = row0 + lane15,      mrowB = row0 + 16 + lane15;
    const int mrowC = row0 + 32 + lane15, mrowD = row0 + 48 + lane15;
    const int fb = fh * 128;
    const int kbase = ADD * 4096 + wc * 1024;   // each wave owns 1024 keys
    const float siA = s1[mrowA], siB = s1[mrowB];
    const float siC = s1[mrowC], siD = s1[mrowD];
    const float tmxA = siA + Mrow[mrowA], tmxB = siB + Mrow[mrowB];
    const float tmxC = siC + Mrow[mrowC], tmxD = siD + Mrow[mrowD];
    const float mCA = fmaxf(tmxA, 0.2f * tmxA) * LOG2E_F;
    const float mCB = fmaxf(tmxB, 0.2f * tmxB) * LOG2E_F;
    const float mCC = fmaxf(tmxC, 0.2f * tmxC) * LOG2E_F;
    const float mCD = fmaxf(tmxD, 0.2f * tmxD) * LOG2E_F;
    const unsigned* __restrict__ mA32 = mask32 + (size_t)mrowA * 256;
    const unsigned* __restrict__ mB32 = mask32 + (size_t)mrowB * 256;
    const unsigned* __restrict__ mC32 = mask32 + (size_t)mrowC * 256;
    const unsigned* __restrict__ mD32 = mask32 + (size_t)mrowD * 256;

    f32x4 accA[8], accB[8], accC[8], accD[8], accLA, accLB, accLC, accLD;
#pragma unroll
    for (int nt = 0; nt < 8; ++nt) {
        f32x4 z = {0.f, 0.f, 0.f, 0.f};
        accA[nt] = z; accB[nt] = z; accC[nt] = z; accD[nt] = z;
    }
    { f32x4 z = {0.f, 0.f, 0.f, 0.f}; accLA = z; accLB = z; accLC = z; accLD = z; }

    s16x8 bones;
#pragma unroll
    for (int j = 0; j < 8; ++j) bones[j] = (short)0x3F80;   // bf16 1.0

    const unsigned vb = (unsigned)(fb + lane15) * 8u;

    s16x8 bA[8], bB[8];
    LOAD_B(bA, kbase)
    unsigned mwA = mA32[kbase >> 5], mwB = mB32[kbase >> 5];
    unsigned mwC = mC32[kbase >> 5], mwD = mD32[kbase >> 5];

#pragma unroll 1
    for (int it = 0; it < 32; it += 2) {
        const int k0 = kbase + it * 32;
        const int k1 = k0 + 32;
        const int k2n = (it + 2 < 32) ? (k0 + 64) : kbase;   // wrap: loaded, unused

        LOAD_B(bB, k1)
        const unsigned mwnA = mA32[k1 >> 5], mwnB = mB32[k1 >> 5];
        const unsigned mwnC = mC32[k1 >> 5], mwnD = mD32[k1 >> 5];

        HALF_STEP(bA, mwA, mwB, mwC, mwD, k0);

        LOAD_B(bA, k2n)
        mwA = mA32[k2n >> 5]; mwB = mB32[k2n >> 5];
        mwC = mC32[k2n >> 5]; mwD = mD32[k2n >> 5];

        HALF_STEP(bB, mwnA, mwnB, mwnC, mwnD, k1);
    }

    // l partials: ones-MFMA reduced over keys; D col 0 holds row sums.
    if (lane15 == 0) {
#pragma unroll
        for (int r = 0; r < 4; ++r) {
            lbuf[wc][0][kg * 4 + r] = accLA[r];
            lbuf[wc][1][kg * 4 + r] = accLB[r];
            lbuf[wc][2][kg * 4 + r] = accLC[r];
            lbuf[wc][3][kg * 4 + r] = accLD[r];
        }
    }

    OUT_PHASE(accA, 0, 0)
    OUT_PHASE(accB, 1, 16)
    OUT_PHASE(accC, 2, 32)
    OUT_PHASE(accD, 3, 48)
}

extern "C" void kernel_launch(void* const* d_in, const int* in_sizes, int n_in,
                              void* d_out, int out_size, void* d_ws, size_t ws_size,
                              hipStream_t stream) {
    (void)in_sizes; (void)n_in; (void)out_size; (void)ws_size;
    const float* x  = (const float*)d_in[0];
    const int*  adj = (const int*)d_in[1];
    const float* W  = (const float*)d_in[2];
    const float* a  = (const float*)d_in[3];
    float* out = (float*)d_out;
    char* ws = (char*)d_ws;
    // total ws use: 12.16 MB (proven-safe budget)
    unsigned short* hTp = (unsigned short*)ws;                      // 4 MB  packed bf16
    float* s1 = (float*)(ws + (4 << 20));                           // 32 KB
    float* s2 = (float*)(ws + (4 << 20) + (32 << 10));              // 32 KB
    float* va = (float*)(ws + (4 << 20) + (64 << 10));              // 2 KB
    float* Mr = (float*)(ws + (4 << 20) + (96 << 10));              // 32 KB
    float* Lp = (float*)(ws + (4 << 20) + (128 << 10));             // 32 KB
    unsigned* mk = (unsigned*)(ws + (4 << 20) + (160 << 10));       // 8 MB

    k0_pack<<<2048, 256, 0, stream>>>(adj, mk);
    k1_gemm<<<512, 256, 0, stream>>>(x, W, hTp);
    kva<<<2, 256, 0, stream>>>(W, a, va);
    k1b_s<<<256, 256, 0, stream>>>(x, va, s1, s2);
    kmax<<<2048, 256, 0, stream>>>(mk, s2, Mr);
    k2_attn<0><<<256, 256, 0, stream>>>(mk, hTp, s1, s2, Mr, Lp, out);
    k2_attn<1><<<256, 256, 0, stream>>>(mk, hTp, s1, s2, Mr, Lp, out);
}